// Round 11
// baseline (251.607 us; speedup 1.0000x reference)
//
#include <hip/hip_runtime.h>
#include <hip/hip_bf16.h>
#include <stdint.h>

typedef __attribute__((ext_vector_type(4))) int i32x4;
typedef __attribute__((ext_vector_type(16))) int i32x16;
typedef signed char s8;

#define M_TOT 8192
#define N_TOT 8192
#define K_TOT 2048
#define W_COUNT (N_TOT * K_TOT)
#define X_COUNT (M_TOT * K_TOT)

// ---------------- 1. fused deterministic reductions: sum|w| (double), max|x| ----------
__global__ void tl_reduce(const float* __restrict__ w, const float* __restrict__ x,
                          double* __restrict__ wsum, float* __restrict__ xmax) {
    const int b = blockIdx.x;
    if (b < 1024) {
        const int tid = b * 256 + threadIdx.x;
        const float4* w4 = (const float4*)w;
        double s = 0.0;
        for (int i = tid; i < W_COUNT / 4; i += 1024 * 256) {
            float4 v = w4[i];
            s += (double)fabsf(v.x) + (double)fabsf(v.y) + (double)fabsf(v.z) + (double)fabsf(v.w);
        }
        #pragma unroll
        for (int off = 32; off > 0; off >>= 1) s += __shfl_down(s, off);
        __shared__ double red[4];
        if ((threadIdx.x & 63) == 0) red[threadIdx.x >> 6] = s;
        __syncthreads();
        if (threadIdx.x == 0) wsum[b] = (red[0] + red[1]) + (red[2] + red[3]);
    } else {
        const int tid = (b - 1024) * 256 + threadIdx.x;
        const float4* x4 = (const float4*)x;
        float m = 0.0f;
        for (int i = tid; i < X_COUNT / 4; i += 1024 * 256) {
            float4 v = x4[i];
            m = fmaxf(m, fmaxf(fmaxf(fabsf(v.x), fabsf(v.y)), fmaxf(fabsf(v.z), fabsf(v.w))));
        }
        #pragma unroll
        for (int off = 32; off > 0; off >>= 1) m = fmaxf(m, __shfl_down(m, off));
        __shared__ float redm[4];
        if ((threadIdx.x & 63) == 0) redm[threadIdx.x >> 6] = m;
        __syncthreads();
        if (threadIdx.x == 0) xmax[b - 1024] = fmaxf(fmaxf(redm[0], redm[1]), fmaxf(redm[2], redm[3]));
    }
}

__global__ void tl_finalize(const double* __restrict__ wsum, const float* __restrict__ xmax,
                            const float* __restrict__ alpha,
                            double* __restrict__ delta, float* __restrict__ qp) {
    const int t = threadIdx.x;
    double s = (wsum[t] + wsum[t + 256]) + (wsum[t + 512] + wsum[t + 768]);
    float m = fmaxf(fmaxf(xmax[t], xmax[t + 256]), fmaxf(xmax[t + 512], xmax[t + 768]));
    #pragma unroll
    for (int off = 32; off > 0; off >>= 1) {
        s += __shfl_down(s, off);
        m = fmaxf(m, __shfl_down(m, off));
    }
    __shared__ double rs[4];
    __shared__ float rm[4];
    if ((t & 63) == 0) { rs[t >> 6] = s; rm[t >> 6] = m; }
    __syncthreads();
    if (t == 0) {
        *delta = 0.7 * (((rs[0] + rs[1]) + (rs[2] + rs[3])) / (double)W_COUNT);
        float mm = fmaxf(fmaxf(rm[0], rm[1]), fmaxf(rm[2], rm[3]));
        qp[0] = 127.0f / mm;                   // x quant scale
        qp[1] = alpha[0] * (mm / 127.0f);      // output scale
    }
}

// ---------------- 2. ternarize w -> i8 fragments (MFMA-ready layout) ----------------
// Fragment f = NB*64 + KB (NB = n>>5, KB = k>>5): 1024 B; lane l holds
// B[NB*32 + (l&31)][KB*32 + (l>>5)*16 .. +16). Stores coalesced (i*16).
__global__ void tl_tern_w(const float* __restrict__ w, const double* __restrict__ delta_p,
                          s8* __restrict__ wbF) {
    const double d = *delta_p;
    const int i = blockIdx.x * 256 + threadIdx.x;     // 1,048,576 threads x 16B
    const int frag = i >> 6, lane = i & 63;
    const int n = (frag >> 6) * 32 + (lane & 31);
    const int k = (frag & 63) * 32 + (lane >> 5) * 16;
    const float* src = w + (size_t)n * K_TOT + k;
    union { s8 c[16]; i32x4 v; } o;
    #pragma unroll
    for (int j = 0; j < 16; j += 4) {
        float4 v = *(const float4*)(src + j);
        float f[4] = {v.x, v.y, v.z, v.w};
        #pragma unroll
        for (int r = 0; r < 4; ++r) {
            double wd = (double)f[r];
            o.c[j + r] = wd > d ? 1 : (wd < -d ? -1 : 0);
        }
    }
    *(i32x4*)(wbF + (size_t)i * 16) = o.v;
}

// ---------------- 3. quantize x -> i8 fragments (reads coalesced, 16B scatter) -----
// thread i: row = i>>7, chunk c = i&127 (16 k-elems). Write to frag
// (MB=row>>5, KB=c>>1) at lane (c&1)*32 + (row&31).
__global__ void tl_quant_x(const float* __restrict__ x, const float* __restrict__ qp,
                           s8* __restrict__ xbF) {
    const float inv = qp[0];
    const int i = blockIdx.x * 256 + threadIdx.x;
    const int row = i >> 7, c = i & 127;
    const float* src = x + (size_t)row * K_TOT + c * 16;
    union { s8 c8[16]; i32x4 v; } o;
    #pragma unroll
    for (int j = 0; j < 16; j += 4) {
        float4 v = *(const float4*)(src + j);
        float f[4] = {v.x, v.y, v.z, v.w};
        #pragma unroll
        for (int r = 0; r < 4; ++r) {
            int q = (int)__builtin_rintf(f[r] * inv);
            q = q > 127 ? 127 : (q < -127 ? -127 : q);
            o.c8[j + r] = (s8)q;
        }
    }
    const size_t dst = ((size_t)(row >> 5) * 64 + (c >> 1)) * 1024 +
                       ((c & 1) * 32 + (row & 31)) * 16;
    *(i32x4*)(xbF + dst) = o.v;
}

// ---------------- 4. LDS-free barrier-free i8 MFMA GEMM (reg-staged fragments) -----
// C[m][n] = out_scale * (sum_k xq[m][k]*wt[n][k]) + bias[n]
// 512 threads = 8 waves (2 wr x 4 wc); wave owns 128x64 of C = 4x2 32x32 frags.
// Per K-tile per wave: 12 x global_load_dwordx4 (8 A + 4 B) fragment loads,
// E/O register double-buffer, prefetch distance = 1 tile, vmcnt(12) counted.
// No LDS, no barriers: waves drift; L1 (32KB = one tile's unique frags)
// absorbs the 4x/2x wave duplication; rect-XCD mapping keeps panels L2-hot.

#define SB    __builtin_amdgcn_sched_barrier(0)
#define VMW(N) asm volatile("s_waitcnt vmcnt(" #N ")" ::: "memory")
#define PRIO1 __builtin_amdgcn_s_setprio(1)
#define PRIO0 __builtin_amdgcn_s_setprio(0)

// issue 12 fragment loads for one K-tile at byte offset KOFF (= t*2048)
#define ISSUE12(NA, NB_, KOFF) do {                                            \
    _Pragma("unroll") for (int m_ = 0; m_ < 4; ++m_)                           \
        _Pragma("unroll") for (int h_ = 0; h_ < 2; ++h_)                       \
            NA[m_][h_] = *(const i32x4*)(aP[m_] + (KOFF) + h_ * 1024);         \
    _Pragma("unroll") for (int n_ = 0; n_ < 2; ++n_)                           \
        _Pragma("unroll") for (int h_ = 0; h_ < 2; ++h_)                       \
            NB_[n_][h_] = *(const i32x4*)(bP[n_] + (KOFF) + h_ * 1024);        \
} while (0)

#define MMH(CA, CB, H) do {                                                    \
    _Pragma("unroll") for (int m_ = 0; m_ < 4; ++m_)                           \
    _Pragma("unroll") for (int n_ = 0; n_ < 2; ++n_)                           \
        acc[m_][n_] = __builtin_amdgcn_mfma_i32_32x32x32_i8(                   \
            CA[m_][H], CB[n_][H], acc[m_][n_], 0, 0, 0);                       \
} while (0)

// consume (CA,CB); optionally issue next tile into (NA,NB_)
#define TILE(CA, CB, NA, NB_, KOFF, DOISS, GATE) do {                          \
    if (DOISS) { ISSUE12(NA, NB_, KOFF); }                                     \
    SB; GATE; SB;                                                              \
    PRIO1; MMH(CA, CB, 0); PRIO0; SB;                                          \
    PRIO1; MMH(CA, CB, 1); PRIO0; SB;                                          \
} while (0)

__global__ __launch_bounds__(512, 2) void tl_gemm_i8(
    const s8* __restrict__ A, const s8* __restrict__ Bm,
    const float* __restrict__ qp, const float* __restrict__ bias,
    float* __restrict__ C) {
    const int t = threadIdx.x;
    const int wid = t >> 6;
    const int l = t & 63;
    const int wr = wid >> 2;   // 0..1
    const int wc = wid & 3;    // 0..3

    // rect XCD ordering: resident 32 blocks/XCD = 4tm x 8tn rectangle (r7 mapping)
    const int bid = blockIdx.x;
    const int xc = bid & 7;
    const int j = bid >> 3;                       // 0..127
    const int tm = xc * 4 + ((j >> 3) & 3);
    const int tn = (j >> 5) * 8 + (j & 7);
    const int row0 = tm * 256, col0 = tn * 256;

    // fragment base pointers: frag(MB,KB) at (MB*64+KB)*1024 + l*16
    const s8* aP[4];
    const s8* bP[2];
    #pragma unroll
    for (int m_ = 0; m_ < 4; ++m_)
        aP[m_] = A + (size_t)(tm * 8 + wr * 4 + m_) * 65536 + l * 16;
    #pragma unroll
    for (int n_ = 0; n_ < 2; ++n_)
        bP[n_] = Bm + (size_t)(tn * 8 + wc * 2 + n_) * 65536 + l * 16;

    const int rl = l & 31, kg = l >> 5;

    i32x16 acc[4][2] = {};
    i32x4 eA[4][2], eB[2][2], oA[4][2], oB[2][2];

    // prologue: issue tile 0 into E
    ISSUE12(eA, eB, 0);

    int koff = 2048;
    #pragma unroll 1
    for (int i = 0; i < 15; ++i) {
        TILE(eA, eB, oA, oB, koff, 1, VMW(12)); koff += 2048;
        TILE(oA, oB, eA, eB, koff, 1, VMW(12)); koff += 2048;
    }
    TILE(eA, eB, oA, oB, koff, 1, VMW(12));   // tile 30, issues tile 31 -> O
    TILE(oA, oB, eA, eB, 0, 0, VMW(0));       // tile 31

    // epilogue: C = out_scale * acc + bias
    // 32x32 C/D layout: col = l&31, row = (reg&3) + 8*(reg>>2) + 4*(l>>5)
    const float osc = qp[1];
    #pragma unroll
    for (int m_ = 0; m_ < 4; ++m_) {
        const int crow = row0 + wr * 128 + m_ * 32 + kg * 4;
        #pragma unroll
        for (int n_ = 0; n_ < 2; ++n_) {
            const int ccol = col0 + wc * 64 + n_ * 32 + rl;
            const float bv = bias[ccol];
            #pragma unroll
            for (int r = 0; r < 16; ++r) {
                const int row = crow + (r & 3) + 8 * (r >> 2);
                C[(size_t)row * N_TOT + ccol] = (float)acc[m_][n_][r] * osc + bv;
            }
        }
    }
}

extern "C" void kernel_launch(void* const* d_in, const int* in_sizes, int n_in,
                              void* d_out, int out_size, void* d_ws, size_t ws_size,
                              hipStream_t stream) {
    const float* x     = (const float*)d_in[0];
    const float* wgt   = (const float*)d_in[1];
    const float* alpha = (const float*)d_in[2];
    const float* bias  = (const float*)d_in[3];
    float* out = (float*)d_out;

    char* ws = (char*)d_ws;
    double* wsum = (double*)ws;               // 8 KB
    float* xmax  = (float*)(ws + 8192);       // 4 KB
    double* delta = (double*)(ws + 12288);
    float* qp     = (float*)(ws + 12304);     // [0]=127/max, [1]=alpha*max/127
    s8* xb = (s8*)(ws + 16384);               // 16 MB, fragment-ordered
    s8* wb = (s8*)(ws + 16384 + (size_t)X_COUNT);  // 16 MB, fragment-ordered

    tl_reduce<<<2048, 256, 0, stream>>>(wgt, x, wsum, xmax);
    tl_finalize<<<1, 256, 0, stream>>>(wsum, xmax, alpha, delta, qp);
    tl_tern_w<<<W_COUNT / (256 * 16), 256, 0, stream>>>(wgt, delta, wb);
    tl_quant_x<<<X_COUNT / (256 * 16), 256, 0, stream>>>(x, qp, xb);
    tl_gemm_i8<<<(M_TOT / 256) * (N_TOT / 256), 512, 0, stream>>>(xb, wb, qp, bias, out);
}

// Round 12
// 207.655 us; speedup vs baseline: 1.2117x; 1.2117x over previous
//
#include <hip/hip_runtime.h>
#include <hip/hip_bf16.h>
#include <stdint.h>

typedef __attribute__((ext_vector_type(4))) int i32x4;
typedef __attribute__((ext_vector_type(16))) int i32x16;
typedef signed char s8;

#define M_TOT 8192
#define N_TOT 8192
#define K_TOT 2048
#define W_COUNT (N_TOT * K_TOT)
#define X_COUNT (M_TOT * K_TOT)

// ---------------- 1. fused deterministic reductions: sum|w| (double), max|x| ----------
__global__ void tl_reduce(const float* __restrict__ w, const float* __restrict__ x,
                          double* __restrict__ wsum, float* __restrict__ xmax) {
    const int b = blockIdx.x;
    if (b < 1024) {
        const int tid = b * 256 + threadIdx.x;
        const float4* w4 = (const float4*)w;
        double s = 0.0;
        for (int i = tid; i < W_COUNT / 4; i += 1024 * 256) {
            float4 v = w4[i];
            s += (double)fabsf(v.x) + (double)fabsf(v.y) + (double)fabsf(v.z) + (double)fabsf(v.w);
        }
        #pragma unroll
        for (int off = 32; off > 0; off >>= 1) s += __shfl_down(s, off);
        __shared__ double red[4];
        if ((threadIdx.x & 63) == 0) red[threadIdx.x >> 6] = s;
        __syncthreads();
        if (threadIdx.x == 0) wsum[b] = (red[0] + red[1]) + (red[2] + red[3]);
    } else {
        const int tid = (b - 1024) * 256 + threadIdx.x;
        const float4* x4 = (const float4*)x;
        float m = 0.0f;
        for (int i = tid; i < X_COUNT / 4; i += 1024 * 256) {
            float4 v = x4[i];
            m = fmaxf(m, fmaxf(fmaxf(fabsf(v.x), fabsf(v.y)), fmaxf(fabsf(v.z), fabsf(v.w))));
        }
        #pragma unroll
        for (int off = 32; off > 0; off >>= 1) m = fmaxf(m, __shfl_down(m, off));
        __shared__ float redm[4];
        if ((threadIdx.x & 63) == 0) redm[threadIdx.x >> 6] = m;
        __syncthreads();
        if (threadIdx.x == 0) xmax[b - 1024] = fmaxf(fmaxf(redm[0], redm[1]), fmaxf(redm[2], redm[3]));
    }
}

__global__ void tl_finalize(const double* __restrict__ wsum, const float* __restrict__ xmax,
                            const float* __restrict__ alpha,
                            double* __restrict__ delta, float* __restrict__ qp) {
    const int t = threadIdx.x;
    double s = (wsum[t] + wsum[t + 256]) + (wsum[t + 512] + wsum[t + 768]);
    float m = fmaxf(fmaxf(xmax[t], xmax[t + 256]), fmaxf(xmax[t + 512], xmax[t + 768]));
    #pragma unroll
    for (int off = 32; off > 0; off >>= 1) {
        s += __shfl_down(s, off);
        m = fmaxf(m, __shfl_down(m, off));
    }
    __shared__ double rs[4];
    __shared__ float rm[4];
    if ((t & 63) == 0) { rs[t >> 6] = s; rm[t >> 6] = m; }
    __syncthreads();
    if (t == 0) {
        *delta = 0.7 * (((rs[0] + rs[1]) + (rs[2] + rs[3])) / (double)W_COUNT);
        float mm = fmaxf(fmaxf(rm[0], rm[1]), fmaxf(rm[2], rm[3]));
        qp[0] = 127.0f / mm;                   // x quant scale
        qp[1] = alpha[0] * (mm / 127.0f);      // output scale
    }
}

// ---------------- 2. ternarize w -> i8 {-1,0,+1} (row-major) ----------------
__global__ void tl_tern_w(const float* __restrict__ w, const double* __restrict__ delta_p,
                          s8* __restrict__ wb) {
    const double d = *delta_p;
    const int i = (blockIdx.x * 256 + threadIdx.x) * 16;
    union { s8 c[16]; i32x4 v; } o;
    #pragma unroll
    for (int j = 0; j < 16; j += 4) {
        float4 v = *(const float4*)(w + i + j);
        float f[4] = {v.x, v.y, v.z, v.w};
        #pragma unroll
        for (int r = 0; r < 4; ++r) {
            double wd = (double)f[r];
            o.c[j + r] = wd > d ? 1 : (wd < -d ? -1 : 0);
        }
    }
    *(i32x4*)(wb + i) = o.v;
}

// ---------------- 3. quantize x -> i8 (RNE, clamp 127), row-major ----------------
__global__ void tl_quant_x(const float* __restrict__ x, const float* __restrict__ qp,
                           s8* __restrict__ xb) {
    const float inv = qp[0];
    const int i = (blockIdx.x * 256 + threadIdx.x) * 16;
    union { s8 c[16]; i32x4 v; } o;
    #pragma unroll
    for (int j = 0; j < 16; j += 4) {
        float4 v = *(const float4*)(x + i + j);
        float f[4] = {v.x, v.y, v.z, v.w};
        #pragma unroll
        for (int r = 0; r < 4; ++r) {
            int q = (int)__builtin_rintf(f[r] * inv);
            q = q > 127 ? 127 : (q < -127 ? -127 : q);
            o.c[j + r] = (s8)q;
        }
    }
    *(i32x4*)(xb + i) = o.v;
}

// ---------------- 4. i8 MFMA GEMM, 256x128 block-tile, 2 blocks/CU, r7 skeleton ----
// C[m][n] = out_scale * (sum_k xq[m][k]*wt[n][k]) + bias[n]
// 256 threads = 4 waves (2 wr x 2 wc); wave owns 128x64 of C = 4x2 32x32 frags
// (per-wave shape IDENTICAL to round-7 best). LDS 72 KiB: A 3x16KB slots,
// B 3x8KB slots -> 2 independent blocks co-reside per CU (the change under test:
// when one block stalls at its barrier, the other block's waves own the SIMD).
// K-loop = r7 skeleton: RD6(h1); lgkm(6); MFMA(h0); stage(t+2) 6 glds; lgkm(0);
// VMW(6) counted gate; BARR; RD6(next h0); MFMA(h1).

#define SB    __builtin_amdgcn_sched_barrier(0)
#define BARR  __builtin_amdgcn_s_barrier()
#define LGKM6 asm volatile("s_waitcnt lgkmcnt(6)" ::: "memory")
#define LGKM0 asm volatile("s_waitcnt lgkmcnt(0)" ::: "memory")
#define VMW(N) asm volatile("s_waitcnt vmcnt(" #N ")" ::: "memory")
#define PRIO1 __builtin_amdgcn_s_setprio(1)
#define PRIO0 __builtin_amdgcn_s_setprio(0)

#define GLDS(SRC, DOFF) __builtin_amdgcn_global_load_lds(                      \
    (const __attribute__((address_space(1))) void*)(SRC),                      \
    (__attribute__((address_space(3))) void*)(lds + (DOFF)), 16, 0, 0)

// 6 reads (4 A + 2 B) for k-half KK of slot S
#define RD6(AR, BR, S, KK) do {                                                \
    _Pragma("unroll") for (int m_ = 0; m_ < 4; ++m_)                           \
        AR[m_] = *(const i32x4*)(lds + (S) * 16384 + wrOff + m_ * 2048 +       \
                                 (lrd ^ ((KK) * 32)));                         \
    _Pragma("unroll") for (int n_ = 0; n_ < 2; ++n_)                           \
        BR[n_] = *(const i32x4*)(lds + 49152 + (S) * 8192 + wcOff + n_ * 2048 + \
                                 (lrd ^ ((KK) * 32)));                         \
} while (0)

#define MM(AR, BR) do {                                                        \
    _Pragma("unroll") for (int m_ = 0; m_ < 4; ++m_)                           \
    _Pragma("unroll") for (int n_ = 0; n_ < 2; ++n_)                           \
        acc[m_][n_] = __builtin_amdgcn_mfma_i32_32x32x32_i8(                   \
            AR[m_], BR[n_], acc[m_][n_], 0, 0, 0);                             \
} while (0)

// A slot 16KB = 4 x 4KB rounds; B slot 8KB = 2 rounds (256 thr x 16B = 4KB)
#define STG_A(SS, KOFF) do {                                                   \
    _Pragma("unroll") for (int j_ = 0; j_ < 4; ++j_)                           \
        GLDS(aSrc + (size_t)(j_ * 64) * K_TOT + (KOFF),                        \
             (SS) * 16384 + j_ * 4096 + L);                                    \
} while (0)
#define STG_B(SS, KOFF) do {                                                   \
    _Pragma("unroll") for (int j_ = 0; j_ < 2; ++j_)                           \
        GLDS(bSrc + (size_t)(j_ * 64) * K_TOT + (KOFF),                        \
             49152 + (SS) * 8192 + j_ * 4096 + L);                             \
} while (0)

// Entering invariant: 6 ds_reads (aE/bE = this tile's h0) + 6 glds(t+1) in flight.
#define KTILE(S, SN, SG, KOFF, DOSTG, GATE, DONEXT) do {                       \
    RD6(aO, bO, S, 1);                                                         \
    SB; LGKM6; SB;                                                             \
    PRIO1; MM(aE, bE); PRIO0; SB;                                              \
    if (DOSTG) { STG_A(SG, KOFF); STG_B(SG, KOFF); }                           \
    SB; LGKM0; SB;                                                             \
    GATE; BARR; SB;                                                            \
    if (DONEXT) RD6(aE, bE, SN, 0);                                            \
    SB;                                                                        \
    PRIO1; MM(aO, bO); PRIO0; SB;                                              \
} while (0)

__global__ __launch_bounds__(256, 2) void tl_gemm_i8(
    const s8* __restrict__ A, const s8* __restrict__ Bm,
    const float* __restrict__ qp, const float* __restrict__ bias,
    float* __restrict__ C) {
    __shared__ __attribute__((aligned(128))) char lds[73728];  // 72 KiB

    const int t = threadIdx.x;
    const int wid = t >> 6;
    const int l = t & 63;
    const int wr = wid >> 1;   // 0..1
    const int wc = wid & 1;    // 0..1

    // XCD rect: 2048 blocks, per XCD 256 (j), resident ~64 = 4tm x 16tn rect
    const int bid = blockIdx.x;
    const int xc = bid & 7;
    const int j = bid >> 3;                       // 0..255
    const int tm = xc * 4 + ((j >> 4) & 3);       // 0..31
    const int tn = (j & 15) + (j >> 6) * 16;      // 0..63
    const int row0 = tm * 256, col0 = tn * 128;

    // staging coords: linear LDS dest byte L (within 4KB round) holds logical
    // offset L ^ (((L>>7)&3)<<4)  (col-chunk ^= (row>>1)&3, involution)
    const int L = t * 16;                 // 0..4095
    const int off = L ^ (((L >> 7) & 3) << 4);
    const int sr = off >> 6;              // 0..63 (row within round)
    const int kb = off & 63;              // 16-aligned k-byte
    const s8* aSrc = A + (size_t)(row0 + sr) * K_TOT + kb;
    const s8* bSrc = Bm + (size_t)(col0 + sr) * K_TOT + kb;

    // ds_read lane constants (32x32 fragment: row = l&31, k-group = l>>5)
    const int rl = l & 31, kg = l >> 5;
    const int lrd = rl * 64 + ((kg ^ ((rl >> 1) & 3)) << 4);
    const int wrOff = wr * 8192;      // 128 rows * 64 B (within A slot)
    const int wcOff = wc * 4096;      // 64 rows * 64 B (within B slot)

    i32x16 acc[4][2] = {};
    i32x4 aE[4], bE[2], aO[4], bO[2];

    // prologue: stage tiles 0 (slot0) and 1 (slot1); gate tile0; first h0 reads
    STG_A(0, 0); STG_B(0, 0);
    STG_A(1, 64); STG_B(1, 64);
    VMW(6); BARR; SB;
    RD6(aE, bE, 0, 0);

    int koff = 128;   // staging byte offset for tile t+2
    #pragma unroll 1
    for (int i = 0; i < 10; ++i) {
        KTILE(0, 1, 2, koff, 1, VMW(6), 1); koff += 64;
        KTILE(1, 2, 0, koff, 1, VMW(6), 1); koff += 64;
        KTILE(2, 0, 1, koff, 1, VMW(6), 1); koff += 64;
    }
    KTILE(0, 1, 0, 0, 0, VMW(0), 1);    // tile 30: drain t31 staging, read its h0
    KTILE(1, 0, 0, 0, 0, (void)0, 0);   // tile 31

    // epilogue: C = out_scale * acc + bias
    // 32x32 C/D layout: col = l&31, row = (reg&3) + 8*(reg>>2) + 4*(l>>5)
    const float osc = qp[1];
    #pragma unroll
    for (int m_ = 0; m_ < 4; ++m_) {
        const int crow = row0 + wr * 128 + m_ * 32 + kg * 4;
        #pragma unroll
        for (int n_ = 0; n_ < 2; ++n_) {
            const int ccol = col0 + wc * 64 + n_ * 32 + rl;
            const float bv = bias[ccol];
            #pragma unroll
            for (int r = 0; r < 16; ++r) {
                const int row = crow + (r & 3) + 8 * (r >> 2);
                C[(size_t)row * N_TOT + ccol] = (float)acc[m_][n_][r] * osc + bv;
            }
        }
    }
}

extern "C" void kernel_launch(void* const* d_in, const int* in_sizes, int n_in,
                              void* d_out, int out_size, void* d_ws, size_t ws_size,
                              hipStream_t stream) {
    const float* x     = (const float*)d_in[0];
    const float* wgt   = (const float*)d_in[1];
    const float* alpha = (const float*)d_in[2];
    const float* bias  = (const float*)d_in[3];
    float* out = (float*)d_out;

    char* ws = (char*)d_ws;
    double* wsum = (double*)ws;               // 8 KB
    float* xmax  = (float*)(ws + 8192);       // 4 KB
    double* delta = (double*)(ws + 12288);
    float* qp     = (float*)(ws + 12304);     // [0]=127/max, [1]=alpha*max/127
    s8* xb = (s8*)(ws + 16384);               // 16 MB, row-major
    s8* wb = (s8*)(ws + 16384 + (size_t)X_COUNT);  // 16 MB, row-major

    tl_reduce<<<2048, 256, 0, stream>>>(wgt, x, wsum, xmax);
    tl_finalize<<<1, 256, 0, stream>>>(wsum, xmax, alpha, delta, qp);
    tl_tern_w<<<W_COUNT / (256 * 16), 256, 0, stream>>>(wgt, delta, wb);
    tl_quant_x<<<X_COUNT / (256 * 16), 256, 0, stream>>>(x, qp, xb);
    tl_gemm_i8<<<(M_TOT / 256) * (N_TOT / 128), 256, 0, stream>>>(xb, wb, qp, bias, out);
}

// Round 13
// 207.566 us; speedup vs baseline: 1.2122x; 1.0004x over previous
//
#include <hip/hip_runtime.h>
#include <hip/hip_bf16.h>
#include <stdint.h>

typedef __attribute__((ext_vector_type(4))) int i32x4;
typedef __attribute__((ext_vector_type(16))) int i32x16;
typedef signed char s8;

#define M_TOT 8192
#define N_TOT 8192
#define K_TOT 2048
#define W_COUNT (N_TOT * K_TOT)
#define X_COUNT (M_TOT * K_TOT)

// ---------------- 1. fused deterministic reductions: sum|w| (double), max|x| ----------
__global__ void tl_reduce(const float* __restrict__ w, const float* __restrict__ x,
                          double* __restrict__ wsum, float* __restrict__ xmax) {
    const int b = blockIdx.x;
    if (b < 1024) {
        const int tid = b * 256 + threadIdx.x;
        const float4* w4 = (const float4*)w;
        double s = 0.0;
        for (int i = tid; i < W_COUNT / 4; i += 1024 * 256) {
            float4 v = w4[i];
            s += (double)fabsf(v.x) + (double)fabsf(v.y) + (double)fabsf(v.z) + (double)fabsf(v.w);
        }
        #pragma unroll
        for (int off = 32; off > 0; off >>= 1) s += __shfl_down(s, off);
        __shared__ double red[4];
        if ((threadIdx.x & 63) == 0) red[threadIdx.x >> 6] = s;
        __syncthreads();
        if (threadIdx.x == 0) wsum[b] = (red[0] + red[1]) + (red[2] + red[3]);
    } else {
        const int tid = (b - 1024) * 256 + threadIdx.x;
        const float4* x4 = (const float4*)x;
        float m = 0.0f;
        for (int i = tid; i < X_COUNT / 4; i += 1024 * 256) {
            float4 v = x4[i];
            m = fmaxf(m, fmaxf(fmaxf(fabsf(v.x), fabsf(v.y)), fmaxf(fabsf(v.z), fabsf(v.w))));
        }
        #pragma unroll
        for (int off = 32; off > 0; off >>= 1) m = fmaxf(m, __shfl_down(m, off));
        __shared__ float redm[4];
        if ((threadIdx.x & 63) == 0) redm[threadIdx.x >> 6] = m;
        __syncthreads();
        if (threadIdx.x == 0) xmax[b - 1024] = fmaxf(fmaxf(redm[0], redm[1]), fmaxf(redm[2], redm[3]));
    }
}

__global__ void tl_finalize(const double* __restrict__ wsum, const float* __restrict__ xmax,
                            const float* __restrict__ alpha,
                            double* __restrict__ delta, float* __restrict__ qp) {
    const int t = threadIdx.x;
    double s = (wsum[t] + wsum[t + 256]) + (wsum[t + 512] + wsum[t + 768]);
    float m = fmaxf(fmaxf(xmax[t], xmax[t + 256]), fmaxf(xmax[t + 512], xmax[t + 768]));
    #pragma unroll
    for (int off = 32; off > 0; off >>= 1) {
        s += __shfl_down(s, off);
        m = fmaxf(m, __shfl_down(m, off));
    }
    __shared__ double rs[4];
    __shared__ float rm[4];
    if ((t & 63) == 0) { rs[t >> 6] = s; rm[t >> 6] = m; }
    __syncthreads();
    if (t == 0) {
        *delta = 0.7 * (((rs[0] + rs[1]) + (rs[2] + rs[3])) / (double)W_COUNT);
        float mm = fmaxf(fmaxf(rm[0], rm[1]), fmaxf(rm[2], rm[3]));
        qp[0] = 127.0f / mm;                   // x quant scale
        qp[1] = alpha[0] * (mm / 127.0f);      // output scale
    }
}

// ---------------- 2. ternarize w -> i8 fragments (MFMA-ready, verified in r8) -------
// Fragment f = NB*64 + KB (NB = n>>5, KB = k>>5): 1024 B; lane l holds
// B[NB*32 + (l&31)][KB*32 + (l>>5)*16 .. +16). Stores coalesced.
__global__ void tl_tern_w(const float* __restrict__ w, const double* __restrict__ delta_p,
                          s8* __restrict__ wbF) {
    const double d = *delta_p;
    const int i = blockIdx.x * 256 + threadIdx.x;     // 1,048,576 threads x 16B
    const int frag = i >> 6, lane = i & 63;
    const int n = (frag >> 6) * 32 + (lane & 31);
    const int k = (frag & 63) * 32 + (lane >> 5) * 16;
    const float* src = w + (size_t)n * K_TOT + k;
    union { s8 c[16]; i32x4 v; } o;
    #pragma unroll
    for (int j = 0; j < 16; j += 4) {
        float4 v = *(const float4*)(src + j);
        float f[4] = {v.x, v.y, v.z, v.w};
        #pragma unroll
        for (int r = 0; r < 4; ++r) {
            double wd = (double)f[r];
            o.c[j + r] = wd > d ? 1 : (wd < -d ? -1 : 0);
        }
    }
    *(i32x4*)(wbF + (size_t)i * 16) = o.v;
}

// ---------------- 3. quantize x -> i8 (RNE, clamp 127), row-major ----------------
__global__ void tl_quant_x(const float* __restrict__ x, const float* __restrict__ qp,
                           s8* __restrict__ xb) {
    const float inv = qp[0];
    const int i = (blockIdx.x * 256 + threadIdx.x) * 16;
    union { s8 c[16]; i32x4 v; } o;
    #pragma unroll
    for (int j = 0; j < 16; j += 4) {
        float4 v = *(const float4*)(x + i + j);
        float f[4] = {v.x, v.y, v.z, v.w};
        #pragma unroll
        for (int r = 0; r < 4; ++r) {
            int q = (int)__builtin_rintf(f[r] * inv);
            q = q > 127 ? 127 : (q < -127 ? -127 : q);
            o.c[j + r] = (s8)q;
        }
    }
    *(i32x4*)(xb + i) = o.v;
}

// ---------------- 4. i8 MFMA GEMM: A via LDS (r7 skeleton), B reg-direct @2-tile ----
// C[m][n] = out_scale * (sum_k xq[m][k]*wt[n][k]) + bias[n]
// 512 threads = 8 waves (2 wr x 4 wc); wave owns 128x64 = 4x2 32x32 frags.
// LDS: A only, 3 slots x 16KB (48 KiB). B: 4 reg-loads/tile from fragment-
// ordered wbF, 3 rotating sets, issued 2 TILES AHEAD (r8's bug was 0-tile
// distance). Per tile: RD_A4(h1); lgkm(4); MFMA h0; issue B(t+2)+gldsA(t+2);
// lgkm(0); VMW(6) [retires B(t+1)+A(t+1), issued a full tile ago]; BARR;
// RD_A4(next h0); MFMA h1. DS/tile: 64 reads + 16KB writes ~ 900 cyc < MFMA 1170.

#define SB    __builtin_amdgcn_sched_barrier(0)
#define BARR  __builtin_amdgcn_s_barrier()
#define LGKM4 asm volatile("s_waitcnt lgkmcnt(4)" ::: "memory")
#define LGKM0 asm volatile("s_waitcnt lgkmcnt(0)" ::: "memory")
#define VMW(N) asm volatile("s_waitcnt vmcnt(" #N ")" ::: "memory")
#define PRIO1 __builtin_amdgcn_s_setprio(1)
#define PRIO0 __builtin_amdgcn_s_setprio(0)

#define GLDS(SRC, DOFF) __builtin_amdgcn_global_load_lds(                      \
    (const __attribute__((address_space(1))) void*)(SRC),                      \
    (__attribute__((address_space(3))) void*)(lds + (DOFF)), 16, 0, 0)

#define RD_A4(AR, S, KK) do {                                                  \
    _Pragma("unroll") for (int m_ = 0; m_ < 4; ++m_)                           \
        AR[m_] = *(const i32x4*)(lds + (S) * 16384 + wrOff + m_ * 2048 +       \
                                 (lrd ^ ((KK) * 32)));                         \
} while (0)

// B frags: [0]=(n0,h0) [1]=(n0,h1) [2]=(n1,h0) [3]=(n1,h1)  (r8-verified)
#define LDB4(BX, BOFF) do {                                                    \
    BX[0] = *(const i32x4*)(bPtr + (BOFF));                                    \
    BX[1] = *(const i32x4*)(bPtr + (BOFF) + 1024);                             \
    BX[2] = *(const i32x4*)(bPtr + (BOFF) + 65536);                            \
    BX[3] = *(const i32x4*)(bPtr + (BOFF) + 65536 + 1024);                     \
} while (0)

#define MMH(AR, BX, H) do {                                                    \
    _Pragma("unroll") for (int m_ = 0; m_ < 4; ++m_) {                         \
        acc[m_][0] = __builtin_amdgcn_mfma_i32_32x32x32_i8(                    \
            AR[m_], BX[0 + (H)], acc[m_][0], 0, 0, 0);                         \
        acc[m_][1] = __builtin_amdgcn_mfma_i32_32x32x32_i8(                    \
            AR[m_], BX[2 + (H)], acc[m_][1], 0, 0, 0);                         \
    }                                                                          \
} while (0)

#define STG_A(SS, KOFF) do {                                                   \
    GLDS(aSrc + (KOFF), (SS) * 16384 + L);                                     \
    GLDS(aSrc + (KOFF) + 262144, (SS) * 16384 + 8192 + L);                     \
} while (0)

// Tile t: slot S = t%3, consumes B-set BC; issues B(t+2) into BN + A(t+2)->SG.
// Entering: 4 ds_reads (aE = h0) in flight; vm queue [B(t+1)4, A(t+1)2].
#define KT(S, SN, SG, BC, BN, KOFF, BOFF, DOISS, GATE, DONEXT) do {            \
    RD_A4(aO, S, 1);                                                           \
    SB; LGKM4; SB;                                                             \
    PRIO1; MMH(aE, BC, 0); PRIO0; SB;                                          \
    if (DOISS) { LDB4(BN, BOFF); STG_A(SG, KOFF); }                            \
    SB; LGKM0; SB;                                                             \
    GATE; BARR; SB;                                                            \
    if (DONEXT) RD_A4(aE, SN, 0);                                              \
    SB;                                                                        \
    PRIO1; MMH(aO, BC, 1); PRIO0; SB;                                          \
} while (0)

__global__ __launch_bounds__(512, 2) void tl_gemm_i8(
    const s8* __restrict__ A, const s8* __restrict__ BmF,
    const float* __restrict__ qp, const float* __restrict__ bias,
    float* __restrict__ C) {
    __shared__ __attribute__((aligned(128))) char lds[49152];  // 48 KiB, A only

    const int t = threadIdx.x;
    const int wid = t >> 6;
    const int l = t & 63;
    const int wr = wid >> 2;   // 0..1
    const int wc = wid & 3;    // 0..3

    // rect XCD ordering: resident 32 blocks/XCD = 4tm x 8tn rectangle (r7)
    const int bid = blockIdx.x;
    const int xc = bid & 7;
    const int j = bid >> 3;                       // 0..127
    const int tm = xc * 4 + ((j >> 3) & 3);
    const int tn = (j >> 5) * 8 + (j & 7);
    const int row0 = tm * 256, col0 = tn * 256;

    // A staging: linear LDS dest byte L holds logical offset L ^ (((L>>7)&3)<<4)
    const int L = t * 16;
    const int off = L ^ (((L >> 7) & 3) << 4);
    const int sr = off >> 6;          // 0..127 (row within half)
    const int kb = off & 63;          // 16-aligned k-byte
    const s8* aSrc = A + (size_t)(row0 + sr) * K_TOT + kb;

    // B fragment pointer: frag(NB, KB) at (NB*64+KB)*1024 + lane*16
    const s8* bPtr = BmF + (size_t)((col0 >> 5) + wc * 2) * 65536 + l * 16;

    // A ds_read lane constants (32x32 fragment: row = l&31, k-group = l>>5)
    const int rl = l & 31, kg = l >> 5;
    const int lrd = rl * 64 + ((kg ^ ((rl >> 1) & 3)) << 4);
    const int wrOff = wr * 8192;      // 128 rows * 64 B

    i32x16 acc[4][2] = {};
    i32x4 aE[4], aO[4], bX[4], bY[4], bZ[4];

    // prologue (FIFO): B0, A0-glds, A1-glds, B1  ->  VMW(6) leaves [A1·2, B1·4]
    LDB4(bX, 0); SB;
    STG_A(0, 0); SB;
    STG_A(1, 64); SB;
    LDB4(bY, 2048); SB;
    VMW(6); SB;              // B0 + A0 retired
    BARR; SB;
    RD_A4(aE, 0, 0); SB;

    int koff = 128;   // A glds k-byte offset for tile t+2
    int boff = 4096;  // B frag byte offset for tile t+2
    #pragma unroll 1
    for (int i = 0; i < 10; ++i) {
        KT(0, 1, 2, bX, bZ, koff, boff, 1, VMW(6), 1); koff += 64; boff += 2048;
        KT(1, 2, 0, bY, bX, koff, boff, 1, VMW(6), 1); koff += 64; boff += 2048;
        KT(2, 0, 1, bZ, bY, koff, boff, 1, VMW(6), 1); koff += 64; boff += 2048;
    }
    KT(0, 1, 0, bX, bZ, 0, 0, 0, VMW(0), 1);    // tile 30: drain A31+B31
    KT(1, 0, 0, bY, bZ, 0, 0, 0, (void)0, 0);   // tile 31 (B31 -> set 31%3=1 = bY)

    // epilogue: C = out_scale * acc + bias
    // 32x32 C/D layout: col = l&31, row = (reg&3) + 8*(reg>>2) + 4*(l>>5)
    const float osc = qp[1];
    #pragma unroll
    for (int m_ = 0; m_ < 4; ++m_) {
        const int crow = row0 + wr * 128 + m_ * 32 + kg * 4;
        #pragma unroll
        for (int n_ = 0; n_ < 2; ++n_) {
            const int ccol = col0 + wc * 64 + n_ * 32 + rl;
            const float bv = bias[ccol];
            #pragma unroll
            for (int r = 0; r < 16; ++r) {
                const int row = crow + (r & 3) + 8 * (r >> 2);
                C[(size_t)row * N_TOT + ccol] = (float)acc[m_][n_][r] * osc + bv;
            }
        }
    }
}

extern "C" void kernel_launch(void* const* d_in, const int* in_sizes, int n_in,
                              void* d_out, int out_size, void* d_ws, size_t ws_size,
                              hipStream_t stream) {
    const float* x     = (const float*)d_in[0];
    const float* wgt   = (const float*)d_in[1];
    const float* alpha = (const float*)d_in[2];
    const float* bias  = (const float*)d_in[3];
    float* out = (float*)d_out;

    char* ws = (char*)d_ws;
    double* wsum = (double*)ws;               // 8 KB
    float* xmax  = (float*)(ws + 8192);       // 4 KB
    double* delta = (double*)(ws + 12288);
    float* qp     = (float*)(ws + 12304);     // [0]=127/max, [1]=alpha*max/127
    s8* xb = (s8*)(ws + 16384);               // 16 MB, row-major
    s8* wb = (s8*)(ws + 16384 + (size_t)X_COUNT);  // 16 MB, fragment-ordered

    tl_reduce<<<2048, 256, 0, stream>>>(wgt, x, wsum, xmax);
    tl_finalize<<<1, 256, 0, stream>>>(wsum, xmax, alpha, delta, qp);
    tl_tern_w<<<W_COUNT / (256 * 16), 256, 0, stream>>>(wgt, delta, wb);
    tl_quant_x<<<X_COUNT / (256 * 16), 256, 0, stream>>>(x, qp, xb);
    tl_gemm_i8<<<(M_TOT / 256) * (N_TOT / 256), 512, 0, stream>>>(xb, wb, qp, bias, out);
}

// Round 14
// 202.830 us; speedup vs baseline: 1.2405x; 1.0233x over previous
//
#include <hip/hip_runtime.h>
#include <hip/hip_bf16.h>
#include <stdint.h>

typedef __attribute__((ext_vector_type(4))) int i32x4;
typedef __attribute__((ext_vector_type(16))) int i32x16;
typedef signed char s8;

#define M_TOT 8192
#define N_TOT 8192
#define K_TOT 2048
#define W_COUNT (N_TOT * K_TOT)
#define X_COUNT (M_TOT * K_TOT)

// ---------------- 1. fused deterministic reductions: sum|w| (double), max|x| ----------
__global__ void tl_reduce(const float* __restrict__ w, const float* __restrict__ x,
                          double* __restrict__ wsum, float* __restrict__ xmax) {
    const int b = blockIdx.x;
    if (b < 1024) {
        const int tid = b * 256 + threadIdx.x;
        const float4* w4 = (const float4*)w;
        double s = 0.0;
        for (int i = tid; i < W_COUNT / 4; i += 1024 * 256) {
            float4 v = w4[i];
            s += (double)fabsf(v.x) + (double)fabsf(v.y) + (double)fabsf(v.z) + (double)fabsf(v.w);
        }
        #pragma unroll
        for (int off = 32; off > 0; off >>= 1) s += __shfl_down(s, off);
        __shared__ double red[4];
        if ((threadIdx.x & 63) == 0) red[threadIdx.x >> 6] = s;
        __syncthreads();
        if (threadIdx.x == 0) wsum[b] = (red[0] + red[1]) + (red[2] + red[3]);
    } else {
        const int tid = (b - 1024) * 256 + threadIdx.x;
        const float4* x4 = (const float4*)x;
        float m = 0.0f;
        for (int i = tid; i < X_COUNT / 4; i += 1024 * 256) {
            float4 v = x4[i];
            m = fmaxf(m, fmaxf(fmaxf(fabsf(v.x), fabsf(v.y)), fmaxf(fabsf(v.z), fabsf(v.w))));
        }
        #pragma unroll
        for (int off = 32; off > 0; off >>= 1) m = fmaxf(m, __shfl_down(m, off));
        __shared__ float redm[4];
        if ((threadIdx.x & 63) == 0) redm[threadIdx.x >> 6] = m;
        __syncthreads();
        if (threadIdx.x == 0) xmax[b - 1024] = fmaxf(fmaxf(redm[0], redm[1]), fmaxf(redm[2], redm[3]));
    }
}

__global__ void tl_finalize(const double* __restrict__ wsum, const float* __restrict__ xmax,
                            const float* __restrict__ alpha,
                            double* __restrict__ delta, float* __restrict__ qp) {
    const int t = threadIdx.x;
    double s = (wsum[t] + wsum[t + 256]) + (wsum[t + 512] + wsum[t + 768]);
    float m = fmaxf(fmaxf(xmax[t], xmax[t + 256]), fmaxf(xmax[t + 512], xmax[t + 768]));
    #pragma unroll
    for (int off = 32; off > 0; off >>= 1) {
        s += __shfl_down(s, off);
        m = fmaxf(m, __shfl_down(m, off));
    }
    __shared__ double rs[4];
    __shared__ float rm[4];
    if ((t & 63) == 0) { rs[t >> 6] = s; rm[t >> 6] = m; }
    __syncthreads();
    if (t == 0) {
        *delta = 0.7 * (((rs[0] + rs[1]) + (rs[2] + rs[3])) / (double)W_COUNT);
        float mm = fmaxf(fmaxf(rm[0], rm[1]), fmaxf(rm[2], rm[3]));
        qp[0] = 127.0f / mm;                   // x quant scale
        qp[1] = alpha[0] * (mm / 127.0f);      // output scale
    }
}

// ---------------- 2. ternarize w -> i8 {-1,0,+1} (row-major) ----------------
__global__ void tl_tern_w(const float* __restrict__ w, const double* __restrict__ delta_p,
                          s8* __restrict__ wb) {
    const double d = *delta_p;
    const int i = (blockIdx.x * 256 + threadIdx.x) * 16;
    union { s8 c[16]; i32x4 v; } o;
    #pragma unroll
    for (int j = 0; j < 16; j += 4) {
        float4 v = *(const float4*)(w + i + j);
        float f[4] = {v.x, v.y, v.z, v.w};
        #pragma unroll
        for (int r = 0; r < 4; ++r) {
            double wd = (double)f[r];
            o.c[j + r] = wd > d ? 1 : (wd < -d ? -1 : 0);
        }
    }
    *(i32x4*)(wb + i) = o.v;
}

// ---------------- 3. quantize x -> i8 (RNE, clamp 127), row-major ----------------
__global__ void tl_quant_x(const float* __restrict__ x, const float* __restrict__ qp,
                           s8* __restrict__ xb) {
    const float inv = qp[0];
    const int i = (blockIdx.x * 256 + threadIdx.x) * 16;
    union { s8 c[16]; i32x4 v; } o;
    #pragma unroll
    for (int j = 0; j < 16; j += 4) {
        float4 v = *(const float4*)(x + i + j);
        float f[4] = {v.x, v.y, v.z, v.w};
        #pragma unroll
        for (int r = 0; r < 4; ++r) {
            int q = (int)__builtin_rintf(f[r] * inv);
            q = q > 127 ? 127 : (q < -127 ? -127 : q);
            o.c[j + r] = (s8)q;
        }
    }
    *(i32x4*)(xb + i) = o.v;
}

// ---------------- 4. i8 MFMA GEMM: r7 skeleton MINUS setprio / MFMA-fences ---------
// ABLATION under test: r7 (best, 177us) had setprio(1)/(0) around every MFMA
// cluster + dense sched_barrier(0) fences. T5 is documented ~0/negative on
// non-8-phase GEMM (m190): prio toggling starves the co-wave's read phase and
// manufactures phase-alternation. This round: identical structure, no setprio,
// SB kept ONLY immediately after counted waits (rule 18 correctness).

#define SB    __builtin_amdgcn_sched_barrier(0)
#define BARR  __builtin_amdgcn_s_barrier()
#define LGKM6 asm volatile("s_waitcnt lgkmcnt(6)" ::: "memory")
#define LGKM0 asm volatile("s_waitcnt lgkmcnt(0)" ::: "memory")
#define VMW(N) asm volatile("s_waitcnt vmcnt(" #N ")" ::: "memory")

#define GLDS(SRC, DOFF) __builtin_amdgcn_global_load_lds(                      \
    (const __attribute__((address_space(1))) void*)(SRC),                      \
    (__attribute__((address_space(3))) void*)(lds + (DOFF)), 16, 0, 0)

// 6 reads (4 A + 2 B) for k-half KK of slot S
#define RD6(AR, BR, S, KK) do {                                                \
    _Pragma("unroll") for (int m_ = 0; m_ < 4; ++m_)                           \
        AR[m_] = *(const i32x4*)(lds + (S) * 16384 + wrOff + m_ * 2048 +       \
                                 (lrd ^ ((KK) * 32)));                         \
    _Pragma("unroll") for (int n_ = 0; n_ < 2; ++n_)                           \
        BR[n_] = *(const i32x4*)(lds + 49152 + (S) * 16384 + wcOff + n_ * 2048 + \
                                 (lrd ^ ((KK) * 32)));                         \
} while (0)

#define MM(AR, BR) do {                                                        \
    _Pragma("unroll") for (int m_ = 0; m_ < 4; ++m_)                           \
    _Pragma("unroll") for (int n_ = 0; n_ < 2; ++n_)                           \
        acc[m_][n_] = __builtin_amdgcn_mfma_i32_32x32x32_i8(                   \
            AR[m_], BR[n_], acc[m_][n_], 0, 0, 0);                             \
} while (0)

#define STG_A(SS, KOFF) do {                                                   \
    GLDS(aSrc + (KOFF), (SS) * 16384 + L);                                     \
    GLDS(aSrc + (KOFF) + 262144, (SS) * 16384 + 8192 + L);                     \
} while (0)
#define STG_B(SS, KOFF) do {                                                   \
    GLDS(bSrc + (KOFF), 49152 + (SS) * 16384 + L);                             \
    GLDS(bSrc + (KOFF) + 262144, 49152 + (SS) * 16384 + 8192 + L);             \
} while (0)

// Entering invariant: 6 reads (aE/bE = this tile's h0) in flight.
#define KTILE(S, SN, SG, KOFF, DOSTG, GATE, DONEXT) do {                       \
    RD6(aO, bO, S, 1);                                                         \
    LGKM6; SB;                                                                 \
    MM(aE, bE);                                                                \
    if (DOSTG) { STG_A(SG, KOFF); STG_B(SG, KOFF); }                           \
    LGKM0; SB;                                                                 \
    GATE; SB;                                                                  \
    BARR;                                                                      \
    if (DONEXT) RD6(aE, bE, SN, 0);                                            \
    MM(aO, bO);                                                                \
} while (0)

__global__ __launch_bounds__(512, 2) void tl_gemm_i8(
    const s8* __restrict__ A, const s8* __restrict__ Bm,
    const float* __restrict__ qp, const float* __restrict__ bias,
    float* __restrict__ C) {
    __shared__ __attribute__((aligned(128))) char lds[98304];  // 96 KiB

    const int t = threadIdx.x;
    const int wid = t >> 6;
    const int l = t & 63;
    const int wr = wid >> 2;   // 0..1
    const int wc = wid & 3;    // 0..3

    // rect XCD ordering: resident 32 blocks/XCD = 4tm x 8tn rectangle
    const int bid = blockIdx.x;
    const int xc = bid & 7;
    const int j = bid >> 3;                       // 0..127
    const int tm = xc * 4 + ((j >> 3) & 3);
    const int tn = (j >> 5) * 8 + (j & 7);
    const int row0 = tm * 256, col0 = tn * 256;

    // staging coords: linear LDS dest byte L holds logical offset
    // off = L ^ (((L>>7)&3)<<4)  i.e. col-chunk ^= (row>>1)&3 (involution)
    const int L = t * 16;
    const int off = L ^ (((L >> 7) & 3) << 4);
    const int sr = off >> 6;          // 0..127 (row within half)
    const int kb = off & 63;          // 16-aligned k-byte
    const s8* aSrc = A + (size_t)(row0 + sr) * K_TOT + kb;
    const s8* bSrc = Bm + (size_t)(col0 + sr) * K_TOT + kb;

    // ds_read lane constants (32x32 fragment: row = l&31, k-group = l>>5)
    const int rl = l & 31, kg = l >> 5;
    const int lrd = rl * 64 + ((kg ^ ((rl >> 1) & 3)) << 4);
    const int wrOff = wr * 8192;      // 128 rows * 64 B
    const int wcOff = wc * 4096;      // 64 rows * 64 B

    i32x16 acc[4][2] = {};
    i32x4 aE[4], bE[2], aO[4], bO[2];

    // prologue: stage tiles 0 (slot0) and 1 (slot1); gate tile0; first h0 reads
    STG_A(0, 0); STG_B(0, 0);
    STG_A(1, 64); STG_B(1, 64);
    VMW(4); SB; BARR;
    RD6(aE, bE, 0, 0);

    int koff = 128;   // staging byte offset for tile t+2
    #pragma unroll 1
    for (int i = 0; i < 10; ++i) {
        KTILE(0, 1, 2, koff, 1, VMW(4), 1); koff += 64;
        KTILE(1, 2, 0, koff, 1, VMW(4), 1); koff += 64;
        KTILE(2, 0, 1, koff, 1, VMW(4), 1); koff += 64;
    }
    KTILE(0, 1, 0, 0, 0, VMW(0), 1);    // tile 30: drain t31 staging, read its h0
    KTILE(1, 0, 0, 0, 0, (void)0, 0);   // tile 31

    // epilogue: C = out_scale * acc + bias
    // 32x32 C/D layout: col = l&31, row = (reg&3) + 8*(reg>>2) + 4*(l>>5)
    const float osc = qp[1];
    #pragma unroll
    for (int m_ = 0; m_ < 4; ++m_) {
        const int crow = row0 + wr * 128 + m_ * 32 + kg * 4;
        #pragma unroll
        for (int n_ = 0; n_ < 2; ++n_) {
            const int ccol = col0 + wc * 64 + n_ * 32 + rl;
            const float bv = bias[ccol];
            #pragma unroll
            for (int r = 0; r < 16; ++r) {
                const int row = crow + (r & 3) + 8 * (r >> 2);
                C[(size_t)row * N_TOT + ccol] = (float)acc[m_][n_][r] * osc + bv;
            }
        }
    }
}

extern "C" void kernel_launch(void* const* d_in, const int* in_sizes, int n_in,
                              void* d_out, int out_size, void* d_ws, size_t ws_size,
                              hipStream_t stream) {
    const float* x     = (const float*)d_in[0];
    const float* wgt   = (const float*)d_in[1];
    const float* alpha = (const float*)d_in[2];
    const float* bias  = (const float*)d_in[3];
    float* out = (float*)d_out;

    char* ws = (char*)d_ws;
    double* wsum = (double*)ws;               // 8 KB
    float* xmax  = (float*)(ws + 8192);       // 4 KB
    double* delta = (double*)(ws + 12288);
    float* qp     = (float*)(ws + 12304);     // [0]=127/max, [1]=alpha*max/127
    s8* xb = (s8*)(ws + 16384);               // 16 MB, row-major
    s8* wb = (s8*)(ws + 16384 + (size_t)X_COUNT);  // 16 MB, row-major

    tl_reduce<<<2048, 256, 0, stream>>>(wgt, x, wsum, xmax);
    tl_finalize<<<1, 256, 0, stream>>>(wsum, xmax, alpha, delta, qp);
    tl_tern_w<<<W_COUNT / (256 * 16), 256, 0, stream>>>(wgt, delta, wb);
    tl_quant_x<<<X_COUNT / (256 * 16), 256, 0, stream>>>(x, qp, xb);
    tl_gemm_i8<<<(M_TOT / 256) * (N_TOT / 256), 512, 0, stream>>>(xb, wb, qp, bias, out);
}